// Round 6
// baseline (277.352 us; speedup 1.0000x reference)
//
#include <hip/hip_runtime.h>
#include <stdint.h>
#include <stddef.h>

// GraphSAGE-mean 2-layer pipeline on MI355X — round 10.
//   h   = relu(feat @ W_init + b_init)                      [200000,128] bf16 (ws)
//   l0: hn = segment_mean(h[src0], dst0); h1 = relu(h[:50000]@Ws + hn@Wn + b)  bf16
//   l1: hn = segment_mean(h1[src1], dst1); out = h1[:10000]@Ws + hn@Wn + b    f32
//
// R10 changes vs R9 (273us; place_fc 80us back at R5 signature):
//  - place_fc fc role: T4 counted-vmcnt pipeline. __syncthreads drained
//    vmcnt(0) every tile (the m97 structural stall), killing the prefetch.
//    Now: stage(t+1); s_waitcnt vmcnt(4) (drains tile t's 4 loads, keeps the
//    4 prefetch loads in flight); raw s_barrier + sched_barrier(0); compute;
//    raw s_barrier. Prefetch survives the barrier.
//  - agg+sage fused per layer into aggsage: block = one 16-dst strip; 4 waves
//    aggregate 16 dsts into a 4KB XOR-swizzled LDS tile (same granule^(row&7)
//    scheme both sides), barrier, then each wave runs the MFMA epilogue for
//    its 2 nt-columns (W frags L2-hot from global). Kills the hn HBM
//    round-trip (25.6 MB), two dispatches, and overlaps MFMA with gathers.
//  - WfS/WfN prep moved to 16 tail blocks of place_fc (consumed by aggsage0,
//    next dispatch). Pipeline: memset, place_fc, aggsage0, aggsage1.

#define DIM 128
constexpr int N_SRC0 = 200000;
constexpr int N_DST0 = 50000;
constexpr int N_DST1 = 10000;
constexpr int E0 = 800000;
constexpr int E1 = 160000;
constexpr int MAXDEG = 64;   // Poisson(16): P(deg>64) ~ e^-42 * 50k — impossible

constexpr int FC_BLOCKS = 1024;     // odd blocks of the fused kernel
constexpr int PLACE_BLOCKS = 1024;  // even blocks of the fused kernel
constexpr int PREP_BLOCKS = 16;     // tail blocks: WfS/WfN fragment prep

typedef __attribute__((ext_vector_type(8))) short bf16x8;   // 8 bf16 = 4 VGPRs
typedef __attribute__((ext_vector_type(4))) float f32x4;    // MFMA C/D

__device__ __forceinline__ uint16_t f2bf(float f) {
  union { float f; uint32_t u; } v; v.f = f;
  return (uint16_t)((v.u + 0x7FFFu + ((v.u >> 16) & 1u)) >> 16);  // RNE
}
__device__ __forceinline__ float bf2f(uint16_t h) {
  union { uint32_t u; float f; } v; v.u = ((uint32_t)h) << 16;
  return v.f;
}

// ---------------------------------------------------------------------------
// fused place + fc_init (+ W prep tail).
//   bid >= 2048: WfS/WfN fragment prep (consumed by aggsage0, next dispatch).
//   even blocks: dst-partitioned edge slot-scatter (partition=(bid>>1)&7).
//   odd blocks: h = relu(feat @ W + b). W frag plane built one-time in the
//     tile LDS (chunk-wise, conflict-free), wv -> VGPRs, then 32-row feat
//     tiles double-buffered via global_load_lds with COUNTED vmcnt(4) +
//     raw barriers (prefetch stays in flight across the barrier).
// ---------------------------------------------------------------------------
__global__ __launch_bounds__(256, 4) void place_fc_kernel(
    const int* __restrict__ src0, const int* __restrict__ dst0,
    const int* __restrict__ src1, const int* __restrict__ dst1,
    int* __restrict__ cnt0, int* __restrict__ cnt1,
    int* __restrict__ eslot0, int* __restrict__ eslot1,
    const float* __restrict__ feat, const float* __restrict__ W_init,
    const float* __restrict__ bias, uint16_t* __restrict__ hout,
    const float* __restrict__ WS_src, const float* __restrict__ WN_src,
    uint16_t* __restrict__ Wf_out) {
  __shared__ __align__(16) float tile[2][4096];   // 2 x 32 rows x 128 cols f32

  if (blockIdx.x >= PLACE_BLOCKS + FC_BLOCKS) {
    // ---------------- W prep role (16 tail blocks) ----------------
    int pid = (blockIdx.x - (PLACE_BLOCKS + FC_BLOCKS)) * 256 + threadIdx.x;
#pragma unroll
    for (int u = 0; u < 8; u++) {
      int gid = pid * 8 + u;                             // 0..32767
      int m = gid >> 14, idx = gid & 16383;
      const float* W = m ? WN_src : WS_src;
      int j = idx & 7, lane = (idx >> 3) & 63, nt = (idx >> 9) & 7, kc = idx >> 12;
      int k = kc * 32 + (lane >> 4) * 8 + j;
      int n = nt * 16 + (lane & 15);
      Wf_out[gid] = f2bf(W[k * DIM + n]);
    }
    return;
  }

  if ((blockIdx.x & 1) == 0) {
    // ---------------- place role ----------------
    int pb = blockIdx.x >> 1;        // 0..PLACE_BLOCKS-1
    int part = pb & 7;
    int bpp  = PLACE_BLOCKS >> 3;    // blocks per partition
    int bidx = pb >> 3;
    const int4* s04 = (const int4*)src0;
    const int4* d04 = (const int4*)dst0;
    const int4* s14 = (const int4*)src1;
    const int4* d14 = (const int4*)dst1;

    // layer 0: dst slice [part*6250, part*6250+6250)
    int lo = part * (N_DST0 / 8), hi = lo + (N_DST0 / 8);
    for (int i = bidx * 256 + threadIdx.x; i < E0 / 4; i += bpp * 256) {
      int4 d = d04[i]; int4 s = s04[i];
      if (d.x >= lo && d.x < hi) { int p = atomicAdd(&cnt0[d.x], 1); if (p < MAXDEG) eslot0[(size_t)d.x * MAXDEG + p] = s.x; }
      if (d.y >= lo && d.y < hi) { int p = atomicAdd(&cnt0[d.y], 1); if (p < MAXDEG) eslot0[(size_t)d.y * MAXDEG + p] = s.y; }
      if (d.z >= lo && d.z < hi) { int p = atomicAdd(&cnt0[d.z], 1); if (p < MAXDEG) eslot0[(size_t)d.z * MAXDEG + p] = s.z; }
      if (d.w >= lo && d.w < hi) { int p = atomicAdd(&cnt0[d.w], 1); if (p < MAXDEG) eslot0[(size_t)d.w * MAXDEG + p] = s.w; }
    }
    // layer 1: dst slice [part*1250, part*1250+1250)
    int lo1 = part * (N_DST1 / 8), hi1 = lo1 + (N_DST1 / 8);
    for (int i = bidx * 256 + threadIdx.x; i < E1 / 4; i += bpp * 256) {
      int4 d = d14[i]; int4 s = s14[i];
      if (d.x >= lo1 && d.x < hi1) { int p = atomicAdd(&cnt1[d.x], 1); if (p < MAXDEG) eslot1[(size_t)d.x * MAXDEG + p] = s.x; }
      if (d.y >= lo1 && d.y < hi1) { int p = atomicAdd(&cnt1[d.y], 1); if (p < MAXDEG) eslot1[(size_t)d.y * MAXDEG + p] = s.y; }
      if (d.z >= lo1 && d.z < hi1) { int p = atomicAdd(&cnt1[d.z], 1); if (p < MAXDEG) eslot1[(size_t)d.z * MAXDEG + p] = s.z; }
      if (d.w >= lo1 && d.w < hi1) { int p = atomicAdd(&cnt1[d.w], 1); if (p < MAXDEG) eslot1[(size_t)d.w * MAXDEG + p] = s.w; }
    }
    return;
  }

  // ---------------- fc role ----------------
  const int tid = threadIdx.x;
  const int w = tid >> 6, lane = tid & 63;
  const int q = lane >> 4, m16 = lane & 15;
  const int sl = w >> 1, nh = w & 1;   // strip-in-tile, nt-half

  // One-time: build the W_init fragment plane in the tile LDS, chunk-wise
  // (conflict-free, R9). Chunk c = (kc*8+nt)*64+lane_c; thread owns 16B.
  {
    uint16_t* wtmp = (uint16_t*)tile;
    for (int u = 0; u < 8; u++) {
      int c = u * 256 + tid;              // 0..2047
      int lane_c = c & 63;
      int nt = (c >> 6) & 7;
      int kc = c >> 9;
      int k0 = kc * 32 + (lane_c >> 4) * 8;
      int n  = nt * 16 + (lane_c & 15);
      bf16x8 frag;
#pragma unroll
      for (int j = 0; j < 8; j++)
        frag[j] = (short)f2bf(W_init[(size_t)(k0 + j) * DIM + n]);
      *(bf16x8*)&wtmp[(size_t)c * 8] = frag;
    }
  }
  __syncthreads();

  bf16x8 wv[4][4];
  {
    const uint16_t* wtmp = (const uint16_t*)tile;
#pragma unroll
    for (int kc = 0; kc < 4; kc++)
#pragma unroll
      for (int jj = 0; jj < 4; jj++)
        wv[kc][jj] = *(const bf16x8*)&wtmp[((kc * 8 + nh * 4 + jj) * 64 + lane) * 8];
  }
  __syncthreads();   // all waves done reading W before tile LDS is recycled

  float bv[4];
#pragma unroll
  for (int j = 0; j < 4; j++) bv[j] = bias[(nh * 4 + j) * 16 + m16];

  const int ntiles = N_SRC0 / 32;   // 6250

  // stage tile t into tile[buf]: LDS dest linear, global source pre-swizzled
  // (granule G ^ (row&7)).  4 global_load_lds issues/wave x 1 KB.
  const int lrow0 = w * 8 + (lane >> 5);
  auto stage = [&](int t, int buf) {
#pragma unroll
    for (int i = 0; i < 4; i++) {
      int row = lrow0 + i * 2;
      int g = (lane & 31) ^ (row & 7);
      const float* gs = feat + (size_t)t * 4096 + row * 128 + g * 4;
      float* ld = &tile[buf][w * 1024 + i * 256];
      __builtin_amdgcn_global_load_lds(
          (const __attribute__((address_space(1))) uint32_t*)gs,
          (__attribute__((address_space(3))) uint32_t*)ld,
          16, 0, 0);
    }
  };

  int t = blockIdx.x >> 1;   // 0..FC_BLOCKS-1
  int cur = 0;
  if (t < ntiles) stage(t, 0);   // 4 loads in flight

  const int trow = sl * 16 + m16;
  const int sw = trow & 7;

  while (t < ntiles) {
    int tn = t + FC_BLOCKS;
    if (tn < ntiles) {
      stage(tn, cur ^ 1);                              // +4 prefetch loads
      asm volatile("s_waitcnt vmcnt(4)" ::: "memory"); // drain tile t's 4 only
    } else {
      asm volatile("s_waitcnt vmcnt(0)" ::: "memory"); // last tile: full drain
    }
    __builtin_amdgcn_s_barrier();       // all waves' tile-t loads now landed
    __builtin_amdgcn_sched_barrier(0);  // rule #18: pin reads below the wait

    f32x4 acc[4];
#pragma unroll
    for (int j = 0; j < 4; j++) acc[j] = (f32x4){0.f, 0.f, 0.f, 0.f};

    const char* rb = (const char*)&tile[cur][0] + trow * 512;
#pragma unroll
    for (int kc = 0; kc < 4; kc++) {
      int g0 = kc * 8 + q * 2;
      float4 x0 = *(const float4*)(rb + ((g0    ) ^ sw) * 16);
      float4 x1 = *(const float4*)(rb + ((g0 + 1) ^ sw) * 16);
      bf16x8 a;
      a[0] = (short)f2bf(x0.x); a[1] = (short)f2bf(x0.y);
      a[2] = (short)f2bf(x0.z); a[3] = (short)f2bf(x0.w);
      a[4] = (short)f2bf(x1.x); a[5] = (short)f2bf(x1.y);
      a[6] = (short)f2bf(x1.z); a[7] = (short)f2bf(x1.w);
#pragma unroll
      for (int j = 0; j < 4; j++)
        acc[j] = __builtin_amdgcn_mfma_f32_16x16x32_bf16(a, wv[kc][j], acc[j], 0, 0, 0);
    }

    int rowb = t * 32 + sl * 16 + q * 4;
#pragma unroll
    for (int j = 0; j < 4; j++)
#pragma unroll
      for (int r = 0; r < 4; r++) {
        float v = fmaxf(acc[j][r] + bv[j], 0.f);
        hout[(size_t)(rowb + r) * DIM + (nh * 4 + j) * 16 + m16] = f2bf(v);
      }

    // protect tile[cur] (fully consumed: MFMA data-deps drained lgkmcnt)
    // before next iteration's stage overwrites it. No vmcnt drain here.
    __builtin_amdgcn_s_barrier();
    cur ^= 1;
    t = tn;
  }
}

// ---------------------------------------------------------------------------
// aggsage: fused segment-mean + SAGE layer. Block = one 16-dst strip.
// Phase 1: wave w aggregates dsts strip*16 + {w, w+4, w+8, w+12} (16-deep
//   uint4 gather ladder, shfl_xor reduce), mean written as bf16 into a 4KB
//   LDS tile with granule^(row&7) XOR swizzle (conflict-free both sides).
// Phase 2: wave w computes nt columns {2w, 2w+1}: XS from global hself,
//   XN from LDS, W fragments L2-hot from global Wf planes. 16 MFMA/wave.
// ---------------------------------------------------------------------------
template <bool ACT, bool OUT_BF16>
__global__ __launch_bounds__(256) void aggsage_kernel(
    const int* __restrict__ eslot, const int* __restrict__ deg,
    const uint16_t* __restrict__ hgat, const uint16_t* __restrict__ hself,
    const uint16_t* __restrict__ WfS, const uint16_t* __restrict__ WfN,
    const float* __restrict__ bS, const float* __restrict__ bN,
    void* __restrict__ outp) {
  __shared__ __align__(16) uint16_t hn_tile[16 * 128];   // 4 KB

  const int strip = blockIdx.x;
  const int tid = threadIdx.x;
  const int w = tid >> 6, lane = tid & 63;
  const int qr = lane >> 4, c = lane & 15;

  // ---- phase 1: aggregate ----
  for (int rr = 0; rr < 4; rr++) {
    int r = w + rr * 4;                      // row in strip (0..15)
    int d = strip * 16 + r;
    const int* sl = eslot + (size_t)d * MAXDEG;
    int dg = deg[d];
    int dgc = dg < MAXDEG ? dg : MAXDEG;

    float a0 = 0.f, a1 = 0.f, a2 = 0.f, a3 = 0.f;
    float a4 = 0.f, a5 = 0.f, a6 = 0.f, a7 = 0.f;

#define ACC4(P)                                                          \
    a0 += bf2f((uint16_t)(P).x); a1 += bf2f((uint16_t)((P).x >> 16));    \
    a2 += bf2f((uint16_t)(P).y); a3 += bf2f((uint16_t)((P).y >> 16));    \
    a4 += bf2f((uint16_t)(P).z); a5 += bf2f((uint16_t)((P).z >> 16));    \
    a6 += bf2f((uint16_t)(P).w); a7 += bf2f((uint16_t)((P).w >> 16));

    int e = 0;
    for (; e + 16 <= dgc; e += 16) {
      int s0 = sl[e + qr];
      int s1 = sl[e + 4 + qr];
      int s2 = sl[e + 8 + qr];
      int s3 = sl[e + 12 + qr];
      uint4 p0 = *(const uint4*)(hgat + (size_t)s0 * DIM + c * 8);
      uint4 p1 = *(const uint4*)(hgat + (size_t)s1 * DIM + c * 8);
      uint4 p2 = *(const uint4*)(hgat + (size_t)s2 * DIM + c * 8);
      uint4 p3 = *(const uint4*)(hgat + (size_t)s3 * DIM + c * 8);
      ACC4(p0); ACC4(p1); ACC4(p2); ACC4(p3);
    }
    for (; e + 8 <= dgc; e += 8) {
      int s0 = sl[e + qr];
      int s1 = sl[e + 4 + qr];
      uint4 p0 = *(const uint4*)(hgat + (size_t)s0 * DIM + c * 8);
      uint4 p1 = *(const uint4*)(hgat + (size_t)s1 * DIM + c * 8);
      ACC4(p0); ACC4(p1);
    }
    for (; e + 4 <= dgc; e += 4) {
      int s0 = sl[e + qr];
      uint4 p0 = *(const uint4*)(hgat + (size_t)s0 * DIM + c * 8);
      ACC4(p0);
    }
    int rem = dgc - e;
    if (qr < rem) {
      int s0 = sl[e + qr];
      uint4 p0 = *(const uint4*)(hgat + (size_t)s0 * DIM + c * 8);
      ACC4(p0);
    }
#undef ACC4

    a0 += __shfl_xor(a0, 16); a0 += __shfl_xor(a0, 32);
    a1 += __shfl_xor(a1, 16); a1 += __shfl_xor(a1, 32);
    a2 += __shfl_xor(a2, 16); a2 += __shfl_xor(a2, 32);
    a3 += __shfl_xor(a3, 16); a3 += __shfl_xor(a3, 32);
    a4 += __shfl_xor(a4, 16); a4 += __shfl_xor(a4, 32);
    a5 += __shfl_xor(a5, 16); a5 += __shfl_xor(a5, 32);
    a6 += __shfl_xor(a6, 16); a6 += __shfl_xor(a6, 32);
    a7 += __shfl_xor(a7, 16); a7 += __shfl_xor(a7, 32);

    if (qr == 0) {
      float inv = 1.f / fmaxf((float)dg, 1.f);
      uint4 o;
      o.x = (uint32_t)f2bf(a0 * inv) | ((uint32_t)f2bf(a1 * inv) << 16);
      o.y = (uint32_t)f2bf(a2 * inv) | ((uint32_t)f2bf(a3 * inv) << 16);
      o.z = (uint32_t)f2bf(a4 * inv) | ((uint32_t)f2bf(a5 * inv) << 16);
      o.w = (uint32_t)f2bf(a6 * inv) | ((uint32_t)f2bf(a7 * inv) << 16);
      int g = c ^ (r & 7);                           // XOR-swizzled granule
      *(uint4*)&hn_tile[r * 128 + g * 8] = o;
    }
  }
  __syncthreads();

  // ---- phase 2: sage MFMA epilogue (wave w -> nt {2w, 2w+1}) ----
  const int q = lane >> 4, m16 = lane & 15;
  const int nt0 = w * 2;

  float bv[2];
#pragma unroll
  for (int j = 0; j < 2; j++)
    bv[j] = bS[(nt0 + j) * 16 + m16] + bN[(nt0 + j) * 16 + m16];

  bf16x8 XS[4], XN[4];
  {
    size_t ro = (size_t)(strip * 16 + m16) * DIM + q * 8;
#pragma unroll
    for (int kc = 0; kc < 4; kc++) {
      XS[kc] = *(const bf16x8*)(hself + ro + kc * 32);
      int g = (q + kc * 4) ^ (m16 & 7);              // inverse of write swizzle
      XN[kc] = *(const bf16x8*)&hn_tile[m16 * 128 + g * 8];
    }
  }

  f32x4 acc[2];
#pragma unroll
  for (int j = 0; j < 2; j++) acc[j] = (f32x4){0.f, 0.f, 0.f, 0.f};

#pragma unroll
  for (int kc = 0; kc < 4; kc++)
#pragma unroll
    for (int j = 0; j < 2; j++) {
      size_t fo = (size_t)((kc * 8 + nt0 + j) * 64 + lane) * 8;
      bf16x8 ws = *(const bf16x8*)&WfS[fo];
      bf16x8 wn = *(const bf16x8*)&WfN[fo];
      acc[j] = __builtin_amdgcn_mfma_f32_16x16x32_bf16(XS[kc], ws, acc[j], 0, 0, 0);
      acc[j] = __builtin_amdgcn_mfma_f32_16x16x32_bf16(XN[kc], wn, acc[j], 0, 0, 0);
    }

  int m0 = strip * 16;
#pragma unroll
  for (int j = 0; j < 2; j++)
#pragma unroll
    for (int r = 0; r < 4; r++) {
      float v = acc[j][r] + bv[j];
      if (ACT) v = fmaxf(v, 0.f);
      size_t o = (size_t)(m0 + q * 4 + r) * DIM + (nt0 + j) * 16 + m16;
      if (OUT_BF16) ((uint16_t*)outp)[o] = f2bf(v);
      else          ((float*)outp)[o] = v;
    }
}

// ---------------------------------------------------------------------------
// Workspace layout (bytes):
//   h      @ 0           200000*128 bf16 = 51,200,000
//   h1     @ 51,200,000   50000*128 bf16 = 12,800,000
//   (hn slot unused since R10)
//   cnt0   @ 76,800,000   50000 int      =    200,000
//   cnt1   @ 77,000,000   10000 int      =     40,000
//   eslot0 @ 77,040,000   50000*64 int   = 12,800,000
//   eslot1 @ 89,840,000   10000*64 int   =  2,560,000
//   Wf     @ 92,400,000   3*16384 bf16   =     98,304  (slot 0 unused)
// ---------------------------------------------------------------------------
extern "C" void kernel_launch(void* const* d_in, const int* in_sizes, int n_in,
                              void* d_out, int out_size, void* d_ws, size_t ws_size,
                              hipStream_t stream) {
  const float* feat   = (const float*)d_in[0];
  const int* src0     = (const int*)d_in[1];
  const int* dst0     = (const int*)d_in[2];
  const int* src1     = (const int*)d_in[3];
  const int* dst1     = (const int*)d_in[4];
  const float* W_init = (const float*)d_in[5];
  const float* b_init = (const float*)d_in[6];
  const float* W_self = (const float*)d_in[7];
  const float* b_self = (const float*)d_in[8];
  const float* W_neigh= (const float*)d_in[9];
  const float* b_neigh= (const float*)d_in[10];

  char* ws = (char*)d_ws;
  uint16_t* h     = (uint16_t*)(ws + 0);
  uint16_t* h1    = (uint16_t*)(ws + 51200000);
  int*      cnt0  = (int*)(ws + 76800000);
  int*      cnt1  = (int*)(ws + 77000000);
  int*      eslot0= (int*)(ws + 77040000);
  int*      eslot1= (int*)(ws + 89840000);
  uint16_t* WfI   = (uint16_t*)(ws + 92400000);
  uint16_t* WfS   = WfI + 16384;
  uint16_t* WfN   = WfS + 16384;

  // zero cnt0+cnt1 (contiguous 240000 B) — graph-capturable async memset
  hipMemsetAsync(ws + 76800000, 0, 240000, stream);

  // fused: edge scatter (even) || h = relu(feat@W_init+b) (odd) || W prep (tail)
  place_fc_kernel<<<PLACE_BLOCKS + FC_BLOCKS + PREP_BLOCKS, 256, 0, stream>>>(
      src0, dst0, src1, dst1, cnt0, cnt1, eslot0, eslot1,
      feat, W_init, b_init, h, W_self, W_neigh, WfS);

  // ---- layer 0: fused segment-mean + sage (h1 bf16, relu) ----
  aggsage_kernel<true, true><<<N_DST0 / 16, 256, 0, stream>>>(
      eslot0, cnt0, h, h, WfS, WfN, b_self, b_neigh, h1);

  // ---- layer 1: fused segment-mean + sage (d_out f32, no act) ----
  aggsage_kernel<false, false><<<N_DST1 / 16, 256, 0, stream>>>(
      eslot1, cnt1, h1, h1, WfS, WfN, b_self, b_neigh, d_out);
}